// Round 11
// baseline (554.187 us; speedup 1.0000x reference)
//
#include <hip/hip_runtime.h>
#include <hip/hip_bf16.h>
#include <hip/hip_fp16.h>

// Self-attention, N=8192 tokens, H=1024, fp32 in/out.
//   1. x -> fp16; Wq/Wk/Wv -> fp16 transposed
//   2. q,k,v = x@W + b        (m97-structure 128x128 GEMM, batched)
//   3. S = q@k^T  fp16        (round 21: 256x256 quad-buffered GEMM with
//      TRUE phase-split schedule: 16-MFMA clusters bracketed by raw
//      s_barriers, ds_reads + stage-issues interleaved between clusters,
//      counted vmcnt gates. Round-10's coarse 1-barrier/K-tile version
//      was neutral vs m97 (~763 TF) — per m196/m233 the fine interleave
//      IS the lever, not the buffering.)
//   4. softmax: one wave per row, register-resident, ballot-prefix
//      compaction -> (idx<<16|half) pairs, zero-padded to x8.
//   5. out = P@v sparse gather, column-sliced (2 MB slice L2-resident
//      per XCD). Plateaued at ~184us.
//
// gemm256 ledger (unchanged from round 10, which PASSED correctness):
//   - 4 LDS buffers x (A 256x32 + B 256x32 fp16) = 128 KB; tile kt ->
//     buf kt&3; during tile kt stage tile kt+3 into buf (kt-1)&3 (its
//     readers' MFMA consumers finished before the previous boundary
//     barrier -> no WAR hazard).
//   - boundary of tile kt gates tile kt+1: outstanding = tiles kt+2,kt+3
//     (8 loads, in-order retirement) -> vmcnt(8); tail vmcnt(4)/vmcnt(0)
//     at kt=29/30. Raw s_barrier (no implicit vmcnt(0) drain).
//   - LDS swizzle: phys slot = logical quad ^ ((row>>1)&3), pre-swizzled
//     on the GLOBAL source address (both-sides rule).
//   - epilogue: acc -> LDS (128x258) -> whole-line coalesced stores.

typedef _Float16 f16x8 __attribute__((ext_vector_type(8)));
typedef float floatx4 __attribute__((ext_vector_type(4)));
typedef float floatx2 __attribute__((ext_vector_type(2)));
typedef unsigned short ushortx8 __attribute__((ext_vector_type(8)));

__device__ __forceinline__ unsigned short f2h(float f) {
  __half h = __float2half(f);
  return __builtin_bit_cast(unsigned short, h);
}
__device__ __forceinline__ float h2f(unsigned short u) {
  return __half2float(__builtin_bit_cast(__half, u));
}

// async global->LDS, 16B per lane. LDS dest is wave-uniform base; HW adds lane*16.
__device__ __forceinline__ void async16(const void* g, void* l) {
  __builtin_amdgcn_global_load_lds(
      (__attribute__((address_space(1))) unsigned int*)(g),
      (__attribute__((address_space(3))) unsigned int*)(l),
      16, 0, 0);
}

// ---------------- conversions / transposes ----------------

__global__ __launch_bounds__(256) void conv_f32_f16(const float* __restrict__ in,
                                                    unsigned short* __restrict__ out,
                                                    long n) {
  long i = ((long)blockIdx.x * 256 + threadIdx.x) * 4;
  if (i + 3 < n) {
    float4 f = *(const float4*)(in + i);
    ushort4 o;
    o.x = f2h(f.x); o.y = f2h(f.y); o.z = f2h(f.z); o.w = f2h(f.w);
    *(ushort4*)(out + i) = o;
  }
}

// in[rows][cols] fp32 -> out[cols][rows] fp16; z selects one of 3 matrices
__global__ __launch_bounds__(256) void transpose_f32_f16_3(const float* __restrict__ in0,
                                                           const float* __restrict__ in1,
                                                           const float* __restrict__ in2,
                                                           unsigned short* __restrict__ out,
                                                           int rows, int cols) {
  const float* in = (blockIdx.z == 0) ? in0 : (blockIdx.z == 1) ? in1 : in2;
  unsigned short* o = out + (size_t)blockIdx.z * rows * cols;
  __shared__ float tile[32][33];
  int bx = blockIdx.x * 32;
  int by = blockIdx.y * 32;
  int tx = threadIdx.x & 31, ty = threadIdx.x >> 5;
  #pragma unroll
  for (int yy = ty; yy < 32; yy += 8)
    tile[yy][tx] = in[(size_t)(by + yy) * cols + bx + tx];
  __syncthreads();
  #pragma unroll
  for (int yy = ty; yy < 32; yy += 8)
    o[(size_t)(bx + yy) * rows + by + tx] = f2h(tile[tx][yy]);
}

// ---- proj GEMM 128x128 (m97 recipe): C = A*B^T + bias, fp16, batched z ----
__global__ __launch_bounds__(256, 4)
void gemm_bt(const unsigned short* __restrict__ A,
             const unsigned short* __restrict__ B,
             int M, int Nn, int K,
             const float* __restrict__ b0, const float* __restrict__ b1,
             const float* __restrict__ b2,
             unsigned short* __restrict__ out) {
  B   += (size_t)blockIdx.z * Nn * K;
  out += (size_t)blockIdx.z * M * Nn;
  const float* bias = (blockIdx.z == 0) ? b0 : (blockIdx.z == 1) ? b1 : b2;
  __shared__ unsigned short smem[128 * 136];
  unsigned short* As = smem;
  unsigned short* Bs = smem + 128 * 32;
  const int tid  = threadIdx.x;
  const int wave = tid >> 6;
  const int lane = tid & 63;
  const int wm = wave >> 1, wn = wave & 1;
  const int quad = lane >> 4, l16 = lane & 15;
  const long bm = (long)blockIdx.y * 128;
  const long bn = (long)blockIdx.x * 128;

  floatx4 acc[4][4] = {};

  const int srow = wave * 32 + (lane >> 2);
  const int scol = (lane & 3) * 8;
  const unsigned short* gA0 = A + (bm + srow) * (long)K + scol;
  const unsigned short* gA1 = gA0 + 16L * K;
  const unsigned short* gB0 = B + (bn + srow) * (long)K + scol;
  const unsigned short* gB1 = gB0 + 16L * K;
  unsigned short* lA0 = &As[(wave * 32) * 32];
  unsigned short* lA1 = &As[(wave * 32 + 16) * 32];
  unsigned short* lB0 = &Bs[(wave * 32) * 32];
  unsigned short* lB1 = &Bs[(wave * 32 + 16) * 32];

  for (int kk = 0; kk < K; kk += 32) {
    async16(gA0 + kk, lA0);
    async16(gA1 + kk, lA1);
    async16(gB0 + kk, lB0);
    async16(gB1 + kk, lB1);
    __syncthreads();
    f16x8 af[4], bfv[4];
    #pragma unroll
    for (int i = 0; i < 4; ++i) {
      af[i]  = *reinterpret_cast<const f16x8*>(&As[(wm * 64 + i * 16 + l16) * 32 + quad * 8]);
      bfv[i] = *reinterpret_cast<const f16x8*>(&Bs[(wn * 64 + i * 16 + l16) * 32 + quad * 8]);
    }
    #pragma unroll
    for (int i = 0; i < 4; ++i)
      #pragma unroll
      for (int j = 0; j < 4; ++j)
        acc[i][j] = __builtin_amdgcn_mfma_f32_16x16x32_f16(af[i], bfv[j], acc[i][j], 0, 0, 0);
    __syncthreads();
  }
  // epilogue via LDS (whole-line stores)
  #pragma unroll
  for (int i = 0; i < 4; ++i) {
    const int row0 = wm * 64 + i * 16 + quad * 4;
    #pragma unroll
    for (int j = 0; j < 4; ++j) {
      const int col = wn * 64 + j * 16 + l16;
      const float cb = bias[bn + col];
      #pragma unroll
      for (int r = 0; r < 4; ++r)
        smem[(row0 + r) * 136 + col] = f2h(acc[i][j][r] + cb);
    }
  }
  __syncthreads();
  #pragma unroll
  for (int u = 0; u < 8; ++u) {
    const int chunk = u * 256 + tid;
    const int row = chunk >> 4;
    const int cc = chunk & 15;
    const ushortx8 val = *reinterpret_cast<const ushortx8*>(&smem[row * 136 + cc * 8]);
    *reinterpret_cast<ushortx8*>(&out[(bm + row) * (long)Nn + bn + cc * 8]) = val;
  }
}

// ---- scores GEMM 256x256, phase-split counted-vmcnt (round 21) ----
// C[8192][8192] = A[8192][1024] * B[8192][1024]^T, fp16 in/out, f32 acc.
// 512 threads = 8 waves (2M x 4N); per-wave output 128x64.
__global__ __launch_bounds__(512, 2)
void gemm256(const unsigned short* __restrict__ A,
             const unsigned short* __restrict__ B,
             unsigned short* __restrict__ out) {
  constexpr int Nd = 8192;
  constexpr int K = 1024;
  __shared__ unsigned short smem[65536];  // 128 KB: 4 bufs x (A 8192 + B 8192)
  const int tid  = threadIdx.x;
  const int lane = tid & 63;
  const int wave = tid >> 6;
  const int wm = wave >> 2, wn = wave & 3;
  const int quad = lane >> 4, l16 = lane & 15;

  // XCD-aware bijective swizzle (1024 blocks % 8 == 0)
  const unsigned lin = blockIdx.y * gridDim.x + blockIdx.x;
  const unsigned nb  = gridDim.x * gridDim.y;          // 1024
  const unsigned swz = (lin & 7u) * (nb >> 3) + (lin >> 3);
  const long bm = (long)(swz >> 5) * 256;              // gridDim.x == 32
  const long bn = (long)(swz & 31u) * 256;

  floatx4 acc[8][4] = {};

  // staging: tile kt -> buf kt&3. chunk c in [0,1024): row=c>>2, phys
  // slot=c&3, logical slot = (c&3)^((row>>1)&3); thread t covers c=t,t+512.
  const int c0 = tid, c1 = tid + 512;
  const int r0 = c0 >> 2, r1 = c1 >> 2;
  const int sl0 = (c0 & 3) ^ ((r0 >> 1) & 3);
  const int sl1 = (c1 & 3) ^ ((r1 >> 1) & 3);
  const unsigned short* gA0 = A + (bm + r0) * (long)K + sl0 * 8;
  const unsigned short* gA1 = A + (bm + r1) * (long)K + sl1 * 8;
  const unsigned short* gB0 = B + (bn + r0) * (long)K + sl0 * 8;
  const unsigned short* gB1 = B + (bn + r1) * (long)K + sl1 * 8;
  const int ldsw0 = (c0 & ~63) * 8;   // wave-uniform ushort offset
  const int ldsw1 = (c1 & ~63) * 8;

  auto STAGE_A = [&](int kt) {
    unsigned short* bufA = smem + (kt & 3) * 16384;
    const int ko = kt * 32;
    async16(gA0 + ko, bufA + ldsw0);
    async16(gA1 + ko, bufA + ldsw1);
  };
  auto STAGE_B = [&](int kt) {
    unsigned short* bufB = smem + (kt & 3) * 16384 + 8192;
    const int ko = kt * 32;
    async16(gB0 + ko, bufB + ldsw0);
    async16(gB1 + ko, bufB + ldsw1);
  };

  // prologue: stage tiles 0,1,2 (A then B per tile -> in-order groups of 4)
  STAGE_A(0); STAGE_B(0);
  STAGE_A(1); STAGE_B(1);
  STAGE_A(2); STAGE_B(2);
  // gate tile 0: 12 outstanding, oldest 4 = tile 0
  asm volatile("s_waitcnt vmcnt(8)" ::: "memory");
  asm volatile("s_barrier" ::: "memory");

  for (int kt = 0; kt < 32; ++kt) {
    const unsigned short* bufA = smem + (kt & 3) * 16384;
    const unsigned short* bufB = bufA + 8192;

    // ---------- phase A: stage A(kt+3) | read B + A-frags 0-3 ----------
    if (kt + 3 < 32) STAGE_A(kt + 3);
    f16x8 bf[4], af[4];
    #pragma unroll
    for (int j = 0; j < 4; ++j) {
      const int R = wn * 64 + j * 16 + l16;
      bf[j] = *reinterpret_cast<const f16x8*>(
          bufB + R * 32 + ((quad ^ ((R >> 1) & 3)) * 8));
    }
    #pragma unroll
    for (int mf = 0; mf < 4; ++mf) {
      const int R = wm * 128 + mf * 16 + l16;
      af[mf] = *reinterpret_cast<const f16x8*>(
          bufA + R * 32 + ((quad ^ ((R >> 1) & 3)) * 8));
    }
    asm volatile("s_barrier" ::: "memory");
    __builtin_amdgcn_s_setprio(1);
    #pragma unroll
    for (int mf = 0; mf < 4; ++mf)
      #pragma unroll
      for (int j = 0; j < 4; ++j)
        acc[mf][j] =
            __builtin_amdgcn_mfma_f32_16x16x32_f16(af[mf], bf[j], acc[mf][j], 0, 0, 0);
    __builtin_amdgcn_s_setprio(0);
    asm volatile("s_barrier" ::: "memory");

    // ---------- phase B: stage B(kt+3) | read A-frags 4-7 ----------
    if (kt + 3 < 32) STAGE_B(kt + 3);
    f16x8 ag[4];
    #pragma unroll
    for (int mf = 0; mf < 4; ++mf) {
      const int R = wm * 128 + (mf + 4) * 16 + l16;
      ag[mf] = *reinterpret_cast<const f16x8*>(
          bufA + R * 32 + ((quad ^ ((R >> 1) & 3)) * 8));
    }
    asm volatile("s_barrier" ::: "memory");
    __builtin_amdgcn_s_setprio(1);
    #pragma unroll
    for (int mf = 0; mf < 4; ++mf)
      #pragma unroll
      for (int j = 0; j < 4; ++j)
        acc[mf + 4][j] =
            __builtin_amdgcn_mfma_f32_16x16x32_f16(ag[mf], bf[j], acc[mf + 4][j], 0, 0, 0);
    __builtin_amdgcn_s_setprio(0);

    // ---------- tile boundary: gate tile kt+1 ----------
    // outstanding after this tile's stages: tiles kt+1..kt+3 (<=12 loads).
    if (kt <= 28)      asm volatile("s_waitcnt vmcnt(8)" ::: "memory");
    else if (kt == 29) asm volatile("s_waitcnt vmcnt(4)" ::: "memory");
    else if (kt == 30) asm volatile("s_waitcnt vmcnt(0)" ::: "memory");
    asm volatile("s_barrier" ::: "memory");
  }

  // epilogue: two wm-halves through LDS (128 x 258 ushorts), whole-line stores
  __syncthreads();
  #pragma unroll
  for (int half = 0; half < 2; ++half) {
    if (wm == half) {
      #pragma unroll
      for (int i = 0; i < 8; ++i)
        #pragma unroll
        for (int j = 0; j < 4; ++j)
          #pragma unroll
          for (int r = 0; r < 4; ++r)
            smem[(i * 16 + quad * 4 + r) * 258 + wn * 64 + j * 16 + l16] =
                f2h(acc[i][j][r]);
    }
    __syncthreads();
    #pragma unroll
    for (int s = 0; s < 8; ++s) {
      const int chunk = s * 512 + tid;          // 4096 chunks of 16B
      const int row = chunk >> 5, cc = chunk & 31;
      *reinterpret_cast<ushortx8*>(
          out + (bm + half * 128 + row) * (long)Nd + bn + cc * 8) =
          *reinterpret_cast<const ushortx8*>(smem + row * 258 + cc * 8);
    }
    __syncthreads();
  }
}

// ---- softmax + compaction: ONE WAVE PER ROW ----
// Stripe = 64 lanes x 8 elems = 512 ushorts; 16 stripes cover the row.
// elem idx = u*512 + lane*8 + e. Exact row max, f32 exp, single f2h
// rounding. Nonzeros packed as (idx<<16|halfbits) pairs via ballot
// prefix-sum, zero-padded to x8. nnz[row] = padded count.
__global__ __launch_bounds__(256) void softmax_compact(unsigned short* __restrict__ S,
                                                       int* __restrict__ nnz, int n) {
  const int wid  = threadIdx.x >> 6;
  const int lane = threadIdx.x & 63;
  const int row  = blockIdx.x * 4 + wid;
  unsigned short* prow = S + ((size_t)row << 13);  // n = 8192

  ushortx8 c[16];
  #pragma unroll
  for (int u = 0; u < 16; ++u)
    c[u] = *reinterpret_cast<const ushortx8*>(&prow[u * 512 + lane * 8]);

  float m0 = -1e30f, m1 = -1e30f, m2 = -1e30f, m3 = -1e30f;
  #pragma unroll
  for (int u = 0; u < 16; ++u) {
    m0 = fmaxf(m0, fmaxf(h2f(c[u][0]), h2f(c[u][4])));
    m1 = fmaxf(m1, fmaxf(h2f(c[u][1]), h2f(c[u][5])));
    m2 = fmaxf(m2, fmaxf(h2f(c[u][2]), h2f(c[u][6])));
    m3 = fmaxf(m3, fmaxf(h2f(c[u][3]), h2f(c[u][7])));
  }
  float m = fmaxf(fmaxf(m0, m1), fmaxf(m2, m3));
  #pragma unroll
  for (int off = 32; off > 0; off >>= 1)
    m = fmaxf(m, __shfl_xor(m, off, 64));

  float s0 = 0.f, s1 = 0.f, s2 = 0.f, s3 = 0.f;
  #pragma unroll
  for (int u = 0; u < 16; ++u) {
    s0 += __expf(h2f(c[u][0]) - m) + __expf(h2f(c[u][4]) - m);
    s1 += __expf(h2f(c[u][1]) - m) + __expf(h2f(c[u][5]) - m);
    s2 += __expf(h2f(c[u][2]) - m) + __expf(h2f(c[u][6]) - m);
    s3 += __expf(h2f(c[u][3]) - m) + __expf(h2f(c[u][7]) - m);
  }
  float s = (s0 + s1) + (s2 + s3);
  #pragma unroll
  for (int off = 32; off > 0; off >>= 1)
    s += __shfl_xor(s, off, 64);
  const float inv = 1.0f / s;

  unsigned int* pairs = (unsigned int*)prow;
  const int cap = 4096 - 8;
  int base = 0;
  #pragma unroll
  for (int u = 0; u < 16; ++u) {
    #pragma unroll
    for (int e = 0; e < 8; ++e) {
      const unsigned short hh = f2h(__expf(h2f(c[u][e]) - m) * inv);
      const unsigned long long mask = __ballot(hh != 0);
      if (hh) {
        const int pos = base + (int)__popcll(mask & ((1ull << lane) - 1ull));
        if (pos < cap)
          pairs[pos] = ((unsigned)(u * 512 + lane * 8 + e) << 16) | hh;
      }
      base += (int)__popcll(mask);
    }
  }
  const int c_cl = base < cap ? base : cap;
  const int padded = (c_cl + 7) & ~7;
  if (lane < padded - c_cl) pairs[c_cl + lane] = 0u;
  if (lane == 0) nnz[row] = padded;
}

// ---- sparse PV, column-sliced (unchanged; 183-185us plateau) ----
__global__ __launch_bounds__(256) void pv_sliced(const unsigned short* __restrict__ S,
                                                 const int* __restrict__ nnz,
                                                 const unsigned short* __restrict__ v,
                                                 float* __restrict__ out,
                                                 int n) {
  const int wave = threadIdx.x >> 6;
  const int lane = threadIdx.x & 63;
  const int colbase = blockIdx.x * 128 + lane * 2;
  const unsigned colbyte = (unsigned)colbase * 2;
  const char* __restrict__ vb = (const char*)v;
  const char* __restrict__ sb = (const char*)S;

  #pragma unroll 1
  for (int r = 0; r < 4; ++r) {
    const int row = blockIdx.y + ((wave << 2) + r) * 512;
    int craw = nnz[row];
    craw = craw < 0 ? 0 : (craw > 4096 ? 4096 : craw);
    const int cnt = __builtin_amdgcn_readfirstlane(craw);
    const unsigned rowbase = (unsigned)row << 14;
    const unsigned pend = rowbase + 16384 - 32;
    unsigned poff = rowbase;
    uint4 q0 = *(const uint4*)(sb + poff);
    uint4 q1 = *(const uint4*)(sb + poff + 16);
    float a0 = 0.f, a1 = 0.f;
    for (int j = 0; j < cnt; j += 8) {
      const unsigned pn = (poff + 32 <= pend) ? poff + 32 : pend;
      const uint4 n0 = *(const uint4*)(sb + pn);
      const uint4 n1 = *(const uint4*)(sb + pn + 16);
      const unsigned p[8] = {q0.x, q0.y, q0.z, q0.w, q1.x, q1.y, q1.z, q1.w};
      #pragma unroll
      for (int u = 0; u < 8; ++u) {
        const ushort2 vv = *(const ushort2*)(vb + (((p[u] & 0xffff0000u) >> 5) + colbyte));
        const float w = h2f((unsigned short)(p[u] & 0xffffu));
        a0 += w * h2f(vv.x);
        a1 += w * h2f(vv.y);
      }
      q0 = n0; q1 = n1; poff = pn;
    }
    floatx2 o = {a0, a1};
    __builtin_nontemporal_store(o, (floatx2*)(out + ((size_t)row << 10) + colbase));
  }
}

// ---------------- launch ----------------
extern "C" void kernel_launch(void* const* d_in, const int* in_sizes, int n_in,
                              void* d_out, int out_size, void* d_ws, size_t ws_size,
                              hipStream_t stream) {
  const int N = 8192, H = 1024;
  const float* x  = (const float*)d_in[0];
  const float* Wq = (const float*)d_in[1];
  const float* bq = (const float*)d_in[2];
  const float* Wk = (const float*)d_in[3];
  const float* bk = (const float*)d_in[4];
  const float* Wv = (const float*)d_in[5];
  const float* bv = (const float*)d_in[6];

  char* p = (char*)d_ws;
  unsigned short* xh  = (unsigned short*)p; p += (size_t)N * H * 2;      // 16 MB
  unsigned short* WT  = (unsigned short*)p; p += (size_t)3 * H * H * 2;  // 6 MB
  unsigned short* qkv = (unsigned short*)p; p += (size_t)3 * N * H * 2;  // 48 MB
  unsigned short* S   = (unsigned short*)p; p += (size_t)N * N * 2;      // 128 MB
  int*            nnz = (int*)p;            p += (size_t)N * 4;          // 32 KB
  if ((size_t)(p - (char*)d_ws) > ws_size) return;
  unsigned short* qh = qkv;
  unsigned short* kh = qkv + (size_t)N * H;
  unsigned short* vh = qkv + (size_t)2 * N * H;

  conv_f32_f16<<<(N * H / 4 + 255) / 256, 256, 0, stream>>>(x, xh, (long)N * H);
  transpose_f32_f16_3<<<dim3(H / 32, H / 32, 3), 256, 0, stream>>>(Wq, Wk, Wv, WT, H, H);

  // batched projections: qkv[z][N][H] fp16 (m97 structure)
  gemm_bt<<<dim3(H / 128, N / 128, 3), 256, 0, stream>>>(xh, WT, N, H, H,
                                                         bq, bk, bv, qkv);

  // scores: S[N][N] fp16, 256^2 phase-split pipeline
  gemm256<<<dim3(N / 256, N / 256), 512, 0, stream>>>(qh, kh, S);

  // softmax + in-place compaction: one wave per row
  softmax_compact<<<N / 4, 256, 0, stream>>>(S, nnz, N);
  // sparse PV gather, column-sliced for per-XCD L2 residency
  pv_sliced<<<dim3(8, N / 16), 256, 0, stream>>>(S, nnz, vh, (float*)d_out, N);
}

// Round 12
// 545.019 us; speedup vs baseline: 1.0168x; 1.0168x over previous
//
#include <hip/hip_runtime.h>
#include <hip/hip_bf16.h>
#include <hip/hip_fp16.h>

// Self-attention, N=8192 tokens, H=1024, fp32 in/out.
// fp16 MFMA GEMMs (mfma_f32_16x16x32_f16, fp32 acc), BT form.
//   1. x -> fp16; Wq/Wk/Wv -> fp16 transposed
//   2. q,k,v = x@W + b      (one batched dispatch, blockIdx.z = which)
//   3. S = q@k^T  fp16      (128 MB ws)
//   4. softmax + in-place compaction: fp16 flushes all but ~200/8192 P
//      entries per row to exact 0 -> (idx<<16|half) pairs, ZERO-PADDED to a
//      multiple of 8 (pad pairs contribute w=0 * v[0] = exactly 0).
//   5. out = P@v sparse gather, column-sliced (slice = 128 cols = 2 MB,
//      L2-resident per XCD via linear%8 dispatch; FETCH 788->28 MB).
// Round 22: REVERT to the round-17 measured-best configuration (538.97us).
// Rounds 18-21 (wave-autonomous softmax, 256^2 quad-buffered and
// phase-split scores GEMMs) were all neutral-to-regressive: both 8-phase
// ports landed at the same ~763 TF as this m97 structure, and both
// softmax rewrites were within noise. Final configuration:
//   - GEMM epilogue stages C tile in LDS -> whole-line stores (no
//     partial-line write-allocate).
//   - softmax: 4-wave block per row, ushort8 vector loads, atomic-compact.
//   - pv: 16 blocks/CU, strided rows, branchless quad prefetch.

typedef _Float16 f16x8 __attribute__((ext_vector_type(8)));
typedef float floatx4 __attribute__((ext_vector_type(4)));
typedef float floatx2 __attribute__((ext_vector_type(2)));
typedef unsigned short ushortx8 __attribute__((ext_vector_type(8)));

__device__ __forceinline__ unsigned short f2h(float f) {
  __half h = __float2half(f);
  return __builtin_bit_cast(unsigned short, h);
}
__device__ __forceinline__ float h2f(unsigned short u) {
  return __half2float(__builtin_bit_cast(__half, u));
}

// async global->LDS, 16B per lane. LDS dest is wave-uniform base; HW adds lane*16.
__device__ __forceinline__ void async16(const void* g, void* l) {
  __builtin_amdgcn_global_load_lds(
      (__attribute__((address_space(1))) unsigned int*)(g),
      (__attribute__((address_space(3))) unsigned int*)(l),
      16, 0, 0);
}

// ---------------- conversions / transposes ----------------

__global__ __launch_bounds__(256) void conv_f32_f16(const float* __restrict__ in,
                                                    unsigned short* __restrict__ out,
                                                    long n) {
  long i = ((long)blockIdx.x * 256 + threadIdx.x) * 4;
  if (i + 3 < n) {
    float4 f = *(const float4*)(in + i);
    ushort4 o;
    o.x = f2h(f.x); o.y = f2h(f.y); o.z = f2h(f.z); o.w = f2h(f.w);
    *(ushort4*)(out + i) = o;
  }
}

// in[rows][cols] fp32 -> out[cols][rows] fp16; z selects one of 3 matrices
__global__ __launch_bounds__(256) void transpose_f32_f16_3(const float* __restrict__ in0,
                                                           const float* __restrict__ in1,
                                                           const float* __restrict__ in2,
                                                           unsigned short* __restrict__ out,
                                                           int rows, int cols) {
  const float* in = (blockIdx.z == 0) ? in0 : (blockIdx.z == 1) ? in1 : in2;
  unsigned short* o = out + (size_t)blockIdx.z * rows * cols;
  __shared__ float tile[32][33];
  int bx = blockIdx.x * 32;
  int by = blockIdx.y * 32;
  int tx = threadIdx.x & 31, ty = threadIdx.x >> 5;
  #pragma unroll
  for (int yy = ty; yy < 32; yy += 8)
    tile[yy][tx] = in[(size_t)(by + yy) * cols + bx + tx];
  __syncthreads();
  #pragma unroll
  for (int yy = ty; yy < 32; yy += 8)
    o[(size_t)(bx + yy) * rows + by + tx] = f2h(tile[tx][yy]);
}

// ---- GEMM 128x128 (m97 recipe): C[M][Nn] = A[M][K]*B[Nn][K]^T, fp16 in, f32 acc ----
// MODE 0: batched proj (blockIdx.z selects W/bias/out; +bias[col], fp16 store)
// MODE 1: plain fp16 store (scores)
// Epilogue: acc -> LDS fp16 tile (aliased over As/Bs; row stride padded to
// 136 ushorts) -> full-line global stores (whole 64B lines, no
// write-allocate fetch).
template <int MODE>
__global__ __launch_bounds__(256, 4)
void gemm_bt(const unsigned short* __restrict__ A,
             const unsigned short* __restrict__ B,
             int M, int Nn, int K,
             const float* __restrict__ b0, const float* __restrict__ b1,
             const float* __restrict__ b2,
             unsigned short* __restrict__ out) {
  if constexpr (MODE == 0) {
    B   += (size_t)blockIdx.z * Nn * K;
    out += (size_t)blockIdx.z * M * Nn;
  }
  const float* bias = (MODE != 0) ? nullptr
                      : (blockIdx.z == 0) ? b0 : (blockIdx.z == 1) ? b1 : b2;
  // smem layout: [As 4096][Bs 4096] during K-loop; whole buffer reused as
  // the 128x136 (padded) fp16 C tile in the epilogue (after final barrier).
  __shared__ unsigned short smem[128 * 136];
  unsigned short* As = smem;
  unsigned short* Bs = smem + 128 * 32;
  const int tid  = threadIdx.x;
  const int wave = tid >> 6;
  const int lane = tid & 63;
  const int wm = wave >> 1, wn = wave & 1;
  const int quad = lane >> 4, l16 = lane & 15;
  const long bm = (long)blockIdx.y * 128;
  const long bn = (long)blockIdx.x * 128;

  floatx4 acc[4][4] = {};

  const int srow = wave * 32 + (lane >> 2);
  const int scol = (lane & 3) * 8;
  const unsigned short* gA0 = A + (bm + srow) * (long)K + scol;
  const unsigned short* gA1 = gA0 + 16L * K;
  const unsigned short* gB0 = B + (bn + srow) * (long)K + scol;
  const unsigned short* gB1 = gB0 + 16L * K;
  unsigned short* lA0 = &As[(wave * 32) * 32];
  unsigned short* lA1 = &As[(wave * 32 + 16) * 32];
  unsigned short* lB0 = &Bs[(wave * 32) * 32];
  unsigned short* lB1 = &Bs[(wave * 32 + 16) * 32];

  for (int kk = 0; kk < K; kk += 32) {
    async16(gA0 + kk, lA0);
    async16(gA1 + kk, lA1);
    async16(gB0 + kk, lB0);
    async16(gB1 + kk, lB1);
    __syncthreads();
    f16x8 af[4], bfv[4];
    #pragma unroll
    for (int i = 0; i < 4; ++i) {
      af[i]  = *reinterpret_cast<const f16x8*>(&As[(wm * 64 + i * 16 + l16) * 32 + quad * 8]);
      bfv[i] = *reinterpret_cast<const f16x8*>(&Bs[(wn * 64 + i * 16 + l16) * 32 + quad * 8]);
    }
    #pragma unroll
    for (int i = 0; i < 4; ++i)
      #pragma unroll
      for (int j = 0; j < 4; ++j)
        acc[i][j] = __builtin_amdgcn_mfma_f32_16x16x32_f16(af[i], bfv[j], acc[i][j], 0, 0, 0);
    __syncthreads();
  }
  // all waves past the final barrier: As/Bs dead, reuse smem as C tile
  #pragma unroll
  for (int i = 0; i < 4; ++i) {
    const int row0 = wm * 64 + i * 16 + quad * 4;
    #pragma unroll
    for (int j = 0; j < 4; ++j) {
      const int col = wn * 64 + j * 16 + l16;
      const float cb = (MODE == 0) ? bias[bn + col] : 0.0f;
      #pragma unroll
      for (int r = 0; r < 4; ++r)
        smem[(row0 + r) * 136 + col] = f2h(acc[i][j][r] + cb);
    }
  }
  __syncthreads();
  // coalesced store: chunk = 16B; 2048 chunks; wave-instr = 4 rows x 256B
  #pragma unroll
  for (int u = 0; u < 8; ++u) {
    const int chunk = u * 256 + tid;
    const int row = chunk >> 4;
    const int cc = chunk & 15;
    const ushortx8 val = *reinterpret_cast<const ushortx8*>(&smem[row * 136 + cc * 8]);
    *reinterpret_cast<ushortx8*>(&out[(bm + row) * (long)Nn + bn + cc * 8]) = val;
  }
}

// ---- softmax + compaction: one block per row ----
// P = softmax(row) in fp32, rounded to fp16; nonzeros packed as
// (idx<<16 | halfbits) u32 pairs into the row's own storage (cap n/2),
// then ZERO-PADDED to a multiple of 8 (zero pair: idx 0, w +0.0 -> fma adds
// exactly 0). nnz[row] = padded count. ushort8 vector loads
// (thread t owns elements [t*32, t*32+32), read as 4 x 16B).
__global__ __launch_bounds__(256) void softmax_compact(unsigned short* __restrict__ S,
                                                       int* __restrict__ nnz, int n) {
  const int row = blockIdx.x;
  const int tid = threadIdx.x;
  const int lane = tid & 63, w = tid >> 6;
  unsigned short* prow = S + (size_t)row * n;

  float v[32];
  float m = -1e30f;
  #pragma unroll
  for (int u = 0; u < 4; ++u) {
    const ushortx8 c = *reinterpret_cast<const ushortx8*>(&prow[tid * 32 + u * 8]);
    #pragma unroll
    for (int e = 0; e < 8; ++e) {
      v[u * 8 + e] = h2f(c[e]);
      m = fmaxf(m, v[u * 8 + e]);
    }
  }
  #pragma unroll
  for (int off = 32; off > 0; off >>= 1) m = fmaxf(m, __shfl_down(m, off, 64));
  __shared__ float redm[4];
  __shared__ int cnt;
  if (lane == 0) redm[w] = m;
  if (tid == 0) cnt = 0;
  __syncthreads();
  m = fmaxf(fmaxf(redm[0], redm[1]), fmaxf(redm[2], redm[3]));

  float s = 0.0f;
  #pragma unroll
  for (int i = 0; i < 32; ++i) {
    v[i] = __expf(v[i] - m);
    s += v[i];
  }
  #pragma unroll
  for (int off = 32; off > 0; off >>= 1) s += __shfl_down(s, off, 64);
  __shared__ float reds[4];
  if (lane == 0) reds[w] = s;
  __syncthreads();
  s = reds[0] + reds[1] + reds[2] + reds[3];
  const float inv = 1.0f / s;

  // all global reads of this row fed the reductions above -> safe to overwrite
  unsigned int* pairs = (unsigned int*)prow;
  const int cap = n / 2;
  #pragma unroll
  for (int i = 0; i < 32; ++i) {
    unsigned short hh = f2h(v[i] * inv);
    if (hh) {
      int p = atomicAdd(&cnt, 1);
      if (p < cap) pairs[p] = ((unsigned int)(tid * 32 + i) << 16) | hh;
    }
  }
  __syncthreads();
  const int c = (cnt < cap) ? cnt : cap;
  const int padded = (c + 7) & ~7;
  if (tid < padded - c) pairs[c + tid] = 0u;  // zero pair: w=0 -> exact no-op
  if (tid == 0) nnz[row] = padded;
}

// ---- sparse PV, column-sliced: out[row][slice cols] = sum_j P_j * v[idx_j][cols] ----
// grid = (8 slices, N/16 row-groups) = 4096 blocks = 16/CU. Slice s =
// cols [128s,128s+128) of v = 2 MB, L2-resident on XCD s (linear%8 dispatch).
// Each wave: 4 STRIDED rows (row = by + (wave*4+r)*512), lane owns 2 cols.
// Next pair-quad prefetched branchlessly during the current 8 gathers; all
// loads via uniform base + 32-bit byte voffset; cnt scalar via readfirstlane,
// clamped to [0,4096].
__global__ __launch_bounds__(256) void pv_sliced(const unsigned short* __restrict__ S,
                                                 const int* __restrict__ nnz,
                                                 const unsigned short* __restrict__ v,
                                                 float* __restrict__ out,
                                                 int n) {
  const int wave = threadIdx.x >> 6;
  const int lane = threadIdx.x & 63;
  const int colbase = blockIdx.x * 128 + lane * 2;
  const unsigned colbyte = (unsigned)colbase * 2;
  const char* __restrict__ vb = (const char*)v;
  const char* __restrict__ sb = (const char*)S;

  #pragma unroll 1
  for (int r = 0; r < 4; ++r) {
    const int row = blockIdx.y + ((wave << 2) + r) * 512;  // strided row map
    int craw = nnz[row];
    craw = craw < 0 ? 0 : (craw > 4096 ? 4096 : craw);
    const int cnt = __builtin_amdgcn_readfirstlane(craw);  // wave-uniform
    const unsigned rowbase = (unsigned)row << 14;          // 16 KB pair slot
    const unsigned pend = rowbase + 16384 - 32;
    unsigned poff = rowbase;
    uint4 q0 = *(const uint4*)(sb + poff);
    uint4 q1 = *(const uint4*)(sb + poff + 16);
    float a0 = 0.f, a1 = 0.f;
    for (int j = 0; j < cnt; j += 8) {
      const unsigned pn = (poff + 32 <= pend) ? poff + 32 : pend;  // branchless clamp
      const uint4 n0 = *(const uint4*)(sb + pn);       // prefetch next quad
      const uint4 n1 = *(const uint4*)(sb + pn + 16);
      const unsigned p[8] = {q0.x, q0.y, q0.z, q0.w, q1.x, q1.y, q1.z, q1.w};
      #pragma unroll
      for (int u = 0; u < 8; ++u) {
        const ushort2 vv = *(const ushort2*)(vb + (((p[u] & 0xffff0000u) >> 5) + colbyte));
        const float w = h2f((unsigned short)(p[u] & 0xffffu));
        a0 += w * h2f(vv.x);
        a1 += w * h2f(vv.y);
      }
      q0 = n0; q1 = n1; poff = pn;
    }
    floatx2 o = {a0, a1};
    __builtin_nontemporal_store(o, (floatx2*)(out + ((size_t)row << 10) + colbase));
  }
}

// ---------------- launch ----------------
extern "C" void kernel_launch(void* const* d_in, const int* in_sizes, int n_in,
                              void* d_out, int out_size, void* d_ws, size_t ws_size,
                              hipStream_t stream) {
  const int N = 8192, H = 1024;
  const float* x  = (const float*)d_in[0];
  const float* Wq = (const float*)d_in[1];
  const float* bq = (const float*)d_in[2];
  const float* Wk = (const float*)d_in[3];
  const float* bk = (const float*)d_in[4];
  const float* Wv = (const float*)d_in[5];
  const float* bv = (const float*)d_in[6];

  char* p = (char*)d_ws;
  unsigned short* xh  = (unsigned short*)p; p += (size_t)N * H * 2;      // 16 MB
  unsigned short* WT  = (unsigned short*)p; p += (size_t)3 * H * H * 2;  // 6 MB
  unsigned short* qkv = (unsigned short*)p; p += (size_t)3 * N * H * 2;  // 48 MB
  unsigned short* S   = (unsigned short*)p; p += (size_t)N * N * 2;      // 128 MB
  int*            nnz = (int*)p;            p += (size_t)N * 4;          // 32 KB
  if ((size_t)(p - (char*)d_ws) > ws_size) return;
  unsigned short* qh = qkv;
  unsigned short* kh = qkv + (size_t)N * H;
  unsigned short* vh = qkv + (size_t)2 * N * H;

  conv_f32_f16<<<(N * H / 4 + 255) / 256, 256, 0, stream>>>(x, xh, (long)N * H);
  transpose_f32_f16_3<<<dim3(H / 32, H / 32, 3), 256, 0, stream>>>(Wq, Wk, Wv, WT, H, H);

  // batched projections: qkv[z][N][H] fp16
  gemm_bt<0><<<dim3(H / 128, N / 128, 3), 256, 0, stream>>>(xh, WT, N, H, H,
                                                            bq, bk, bv, qkv);

  // scores: S[N][N] fp16
  gemm_bt<1><<<dim3(N / 128, N / 128), 256, 0, stream>>>(qh, kh, N, N, H,
                                                         nullptr, nullptr, nullptr, S);
  // softmax + in-place compaction to zero-padded sparse pairs
  softmax_compact<<<N, 256, 0, stream>>>(S, nnz, N);
  // sparse PV gather, column-sliced for per-XCD L2 residency (16 blocks/CU)
  pv_sliced<<<dim3(8, N / 16), 256, 0, stream>>>(S, nnz, vh, (float*)d_out, N);
}